// Round 1
// baseline (1870.512 us; speedup 1.0000x reference)
//
#include <hip/hip_runtime.h>

namespace {

constexpr int kC     = 16;
constexpr int kN     = 8192;
constexpr int kH     = 181;
constexpr int kOut   = 3;
constexpr int kTileN = 16;          // rows per block
constexpr int kThreads = 192;       // 3 waves; threads 0..180 own neuron o
constexpr int kLRow  = 2 * kH + 2;  // 364 floats -> 1456B row stride, 16B aligned
constexpr float kOmega = 30.0f;
constexpr float kS2    = 100.0f;    // SCALE^2

// One hidden Gabor layer for one output neuron o, kTileN rows.
// rb/wb are LDS buffers [kTileN][kLRow] holding (re,im) interleaved per neuron.
__device__ __forceinline__ void hidden_layer(
    const float* __restrict__ rb, float* __restrict__ wb,
    const float* __restrict__ Wa, const float* __restrict__ Wb,   // [kH][kH][2], model-offset applied
    const float* __restrict__ ba, const float* __restrict__ bb,   // [kH][2], bias-offset applied
    int o)
{
    float ar[kTileN], ai[kTileN], br[kTileN], bi[kTileN];
    const float2 bav = *reinterpret_cast<const float2*>(&ba[o * 2]);
    const float2 bbv = *reinterpret_cast<const float2*>(&bb[o * 2]);
#pragma unroll
    for (int r = 0; r < kTileN; ++r) {
        ar[r] = bav.x; ai[r] = bav.y; br[r] = bbv.x; bi[r] = bbv.y;
    }

    for (int i = 0; i < kH - 1; i += 2) {
        const float2 wa0 = *reinterpret_cast<const float2*>(&Wa[(i * kH + o) * 2]);
        const float2 wa1 = *reinterpret_cast<const float2*>(&Wa[((i + 1) * kH + o) * 2]);
        const float2 wb0 = *reinterpret_cast<const float2*>(&Wb[(i * kH + o) * 2]);
        const float2 wb1 = *reinterpret_cast<const float2*>(&Wb[((i + 1) * kH + o) * 2]);
#pragma unroll
        for (int r = 0; r < kTileN; ++r) {
            const float4 x = *reinterpret_cast<const float4*>(&rb[r * kLRow + i * 2]);
            // complex acc += x * w   (x = (x.x + i x.y), (x.z + i x.w))
            ar[r] = fmaf(x.x, wa0.x, ar[r]); ar[r] = fmaf(-x.y, wa0.y, ar[r]);
            ai[r] = fmaf(x.x, wa0.y, ai[r]); ai[r] = fmaf( x.y, wa0.x, ai[r]);
            br[r] = fmaf(x.x, wb0.x, br[r]); br[r] = fmaf(-x.y, wb0.y, br[r]);
            bi[r] = fmaf(x.x, wb0.y, bi[r]); bi[r] = fmaf( x.y, wb0.x, bi[r]);
            ar[r] = fmaf(x.z, wa1.x, ar[r]); ar[r] = fmaf(-x.w, wa1.y, ar[r]);
            ai[r] = fmaf(x.z, wa1.y, ai[r]); ai[r] = fmaf( x.w, wa1.x, ai[r]);
            br[r] = fmaf(x.z, wb1.x, br[r]); br[r] = fmaf(-x.w, wb1.y, br[r]);
            bi[r] = fmaf(x.z, wb1.y, bi[r]); bi[r] = fmaf( x.w, wb1.x, bi[r]);
        }
    }
    {   // tail i = 180
        const int i = kH - 1;
        const float2 wa0 = *reinterpret_cast<const float2*>(&Wa[(i * kH + o) * 2]);
        const float2 wb0 = *reinterpret_cast<const float2*>(&Wb[(i * kH + o) * 2]);
#pragma unroll
        for (int r = 0; r < kTileN; ++r) {
            const float2 x = *reinterpret_cast<const float2*>(&rb[r * kLRow + i * 2]);
            ar[r] = fmaf(x.x, wa0.x, ar[r]); ar[r] = fmaf(-x.y, wa0.y, ar[r]);
            ai[r] = fmaf(x.x, wa0.y, ai[r]); ai[r] = fmaf( x.y, wa0.x, ai[r]);
            br[r] = fmaf(x.x, wb0.x, br[r]); br[r] = fmaf(-x.y, wb0.y, br[r]);
            bi[r] = fmaf(x.x, wb0.y, bi[r]); bi[r] = fmaf( x.y, wb0.x, bi[r]);
        }
    }

#pragma unroll
    for (int r = 0; r < kTileN; ++r) {
        const float mag = kS2 * (ar[r]*ar[r] + ai[r]*ai[r] + br[r]*br[r] + bi[r]*bi[r]);
        const float amp = __expf(fmaf(-kOmega, ai[r], -mag));
        const float ph  = kOmega * ar[r];
        float2 v; v.x = amp * __cosf(ph); v.y = amp * __sinf(ph);
        *reinterpret_cast<float2*>(&wb[r * kLRow + o * 2]) = v;
    }
}

__global__ __launch_bounds__(kThreads) void wire_fwd_f32(
    const float* __restrict__ inp, const int* __restrict__ indices,
    const int* __restrict__ model_idx, const int* __restrict__ bias_idx,
    const float* __restrict__ W0a, const float* __restrict__ b0a,
    const float* __restrict__ W0b, const float* __restrict__ b0b,
    const float* __restrict__ W1a, const float* __restrict__ b1a,
    const float* __restrict__ W1b, const float* __restrict__ b1b,
    const float* __restrict__ W2a, const float* __restrict__ b2a,
    const float* __restrict__ W2b, const float* __restrict__ b2b,
    const float* __restrict__ Wf, const float* __restrict__ bf,
    float* __restrict__ out)
{
    __shared__ float xin[kTileN * 2];
    __shared__ float bufA[kTileN * kLRow];
    __shared__ float bufB[kTileN * kLRow];

    // XCD-aware swizzle: 8192 blocks, 8 XCDs -> each XCD gets 1024 contiguous
    // logical blocks = 2 consecutive c's (~2MB of hidden weights, fits 4MB L2).
    const int d = blockIdx.x;
    const int l = (d & 7) * ((kC * (kN / kTileN)) / 8) + (d >> 3);
    const int c  = l / (kN / kTileN);
    const int t  = l % (kN / kTileN);
    const int n0 = t * kTileN;

    const int src = indices[c];
    const int m   = model_idx[c];
    const int bix = bias_idx[c];
    const int o   = threadIdx.x;

    if (o < kTileN * 2) xin[o] = inp[((size_t)src * kN + n0) * 2 + o];
    __syncthreads();

    // ---- layer 0: real 2->181 linear + Gabor activation ----
    if (o < kH) {
        const float w0a0 = W0a[(m * 2 + 0) * kH + o];
        const float w0a1 = W0a[(m * 2 + 1) * kH + o];
        const float w0b0 = W0b[(m * 2 + 0) * kH + o];
        const float w0b1 = W0b[(m * 2 + 1) * kH + o];
        const float b0av = b0a[bix * kH + o];
        const float b0bv = b0b[bix * kH + o];
#pragma unroll
        for (int r = 0; r < kTileN; ++r) {
            const float x0 = xin[r * 2 + 0], x1 = xin[r * 2 + 1];
            const float la = fmaf(x1, w0a1, fmaf(x0, w0a0, b0av));
            const float lb = fmaf(x1, w0b1, fmaf(x0, w0b0, b0bv));
            const float amp = __expf(-kS2 * fmaf(la, la, lb * lb));
            const float ph  = kOmega * la;
            float2 v; v.x = amp * __cosf(ph); v.y = amp * __sinf(ph);
            *reinterpret_cast<float2*>(&bufA[r * kLRow + o * 2]) = v;
        }
    }
    __syncthreads();

    const size_t wstride = (size_t)kH * kH * 2;
    // ---- hidden layer 1: bufA -> bufB ----
    if (o < kH)
        hidden_layer(bufA, bufB, W1a + (size_t)m * wstride, W1b + (size_t)m * wstride,
                     b1a + (size_t)bix * kH * 2, b1b + (size_t)bix * kH * 2, o);
    __syncthreads();
    // ---- hidden layer 2: bufB -> bufA ----
    if (o < kH)
        hidden_layer(bufB, bufA, W2a + (size_t)m * wstride, W2b + (size_t)m * wstride,
                     b2a + (size_t)bix * kH * 2, b2b + (size_t)bix * kH * 2, o);
    __syncthreads();

    // ---- final complex 181->3 linear, real part ----
    if (o < kTileN * kOut) {
        const int r  = o / kOut;
        const int oo = o % kOut;
        float acc = bf[(bix * kOut + oo) * 2];   // real part of bias
        const float* wfm = Wf + (size_t)m * kH * kOut * 2;
        for (int i = 0; i < kH; ++i) {
            const float2 w = *reinterpret_cast<const float2*>(&wfm[(i * kOut + oo) * 2]);
            const float xr = bufA[r * kLRow + i * 2 + 0];
            const float xi = bufA[r * kLRow + i * 2 + 1];
            acc = fmaf(xr, w.x, acc);
            acc = fmaf(-xi, w.y, acc);
        }
        out[((size_t)c * kN + n0 + r) * kOut + oo] = acc;
    }
}

}  // namespace

extern "C" void kernel_launch(void* const* d_in, const int* in_sizes, int n_in,
                              void* d_out, int out_size, void* d_ws, size_t ws_size,
                              hipStream_t stream) {
    const float* inp       = (const float*)d_in[0];
    const int*   indices   = (const int*)  d_in[1];
    const int*   model_idx = (const int*)  d_in[2];
    const int*   bias_idx  = (const int*)  d_in[3];
    const float* W0a = (const float*)d_in[4];
    const float* b0a = (const float*)d_in[5];
    const float* W0b = (const float*)d_in[6];
    const float* b0b = (const float*)d_in[7];
    const float* W1a = (const float*)d_in[8];
    const float* b1a = (const float*)d_in[9];
    const float* W1b = (const float*)d_in[10];
    const float* b1b = (const float*)d_in[11];
    const float* W2a = (const float*)d_in[12];
    const float* b2a = (const float*)d_in[13];
    const float* W2b = (const float*)d_in[14];
    const float* b2b = (const float*)d_in[15];
    const float* Wf  = (const float*)d_in[16];
    const float* bff = (const float*)d_in[17];
    float* out = (float*)d_out;

    const int nblocks = kC * (kN / kTileN);   // 8192
    wire_fwd_f32<<<dim3(nblocks), dim3(kThreads), 0, stream>>>(
        inp, indices, model_idx, bias_idx,
        W0a, b0a, W0b, b0b, W1a, b1a, W1b, b1b,
        W2a, b2a, W2b, b2b, Wf, bff, out);
}

// Round 2
// 656.034 us; speedup vs baseline: 2.8512x; 2.8512x over previous
//
#include <hip/hip_runtime.h>

typedef _Float16 f16;
typedef _Float16 f16x2 __attribute__((ext_vector_type(2)));
typedef _Float16 f16x8 __attribute__((ext_vector_type(8)));
typedef float f32x4 __attribute__((ext_vector_type(4)));

namespace {

constexpr int kC = 16, kN = 8192, kH = 181, kOut = 3;
constexpr int kMB = 64;            // rows per block
constexpr int kKpad = 384;         // 12 ksteps * 32
constexpr int kNT = 48;            // n-tiles of 16 cols (Npad = 768)
constexpr int kKS = 12;            // k-steps of 32
constexpr int kRowB = kKpad * 2;   // 768 bytes per LDS activation row
constexpr float kOmega = 30.f, kS2 = 100.f;

constexpr size_t kWLayerStride = (size_t)kNT * kKS * 64 * 8;  // f16 elems per (c,layer)
constexpr size_t kWfOff = kWLayerStride * kC * 2;             // f16 elems
constexpr size_t kWfStride = (size_t)kKS * 64 * 8;

// XOR-swizzled LDS address: row stride 768B would be a 16-way bank conflict on
// ds_read_b128 (lanes differ only in row); XOR of (row&7) into bits 4..6
// spreads 16 lanes over 8 16B slots -> 2-way (free).
__device__ __forceinline__ int swz(int row, int colb) {
  return row * kRowB + (colb ^ ((row & 7) << 4));
}

// ---- prep: pack hidden-layer complex weights (model-gathered) into fp16
// B-fragment order ws[c][L][nt][ks][lane][8].
// Real expansion: K rows 2i (x_re) / 2i+1 (x_im); N cols 4o+comp with
// comp = (la_re, la_im, lb_re, lb_im).
__global__ __launch_bounds__(768) void prep_hidden(
    const int* __restrict__ model_idx,
    const float* __restrict__ W1a, const float* __restrict__ W1b,
    const float* __restrict__ W2a, const float* __restrict__ W2b,
    f16* __restrict__ ws)
{
  __shared__ float s[kH][2][4][2];   // [i][branch][o_sub][reim]
  const int bid = blockIdx.x;
  const int c  = bid / (2 * kNT);
  const int L  = (bid / kNT) % 2;
  const int nt = bid % kNT;
  const int m  = model_idx[c];
  const float* Wa = (L == 0 ? W1a : W2a) + (size_t)m * kH * kH * 2;
  const float* Wb = (L == 0 ? W1b : W2b) + (size_t)m * kH * kH * 2;
  const int t = threadIdx.x;
  if (t < 2 * kH) {
    const int i = t >> 1, br = t & 1;
    const float* src = (br ? Wb : Wa) + ((size_t)i * kH + nt * 4) * 2;
#pragma unroll
    for (int e = 0; e < 8; ++e) {
      const int osub = e >> 1, reim = e & 1;
      s[i][br][osub][reim] = (nt * 4 + osub < kH) ? src[osub * 2 + reim] : 0.f;
    }
  }
  __syncthreads();
  const int ks = t >> 6, lane = t & 63;
  const int kg = lane >> 4, l15 = lane & 15;
  const int osub = l15 >> 2, comp = l15 & 3, br = comp >> 1;
  const int o = nt * 4 + osub;
  f16x8 v;
#pragma unroll
  for (int j = 0; j < 8; ++j) {
    const int k = ks * 32 + kg * 8 + j;
    float f = 0.f;
    if (k < 2 * kH && o < kH) {
      const int i = k >> 1, kodd = k & 1;
      const int reim = kodd ? (1 - (comp & 1)) : (comp & 1);
      f = s[i][br][osub][reim];
      if (kodd && !(comp & 1)) f = -f;   // -w_im for real-output cols
    }
    v[j] = (f16)f;
  }
  *(f16x8*)&ws[(((size_t)(c * 2 + L) * kNT + nt) * kKS + ks) * 512 + lane * 8] = v;
}

// ---- prep: final layer (real part only): col j<3, k=2i -> wf_re, 2i+1 -> -wf_im
__global__ __launch_bounds__(768) void prep_final(
    const int* __restrict__ model_idx, const float* __restrict__ Wf,
    f16* __restrict__ ws)
{
  const int c = blockIdx.x;
  const int m = model_idx[c];
  const int t = threadIdx.x;
  const int ks = t >> 6, lane = t & 63;
  const int kg = lane >> 4, col = lane & 15;
  f16x8 v;
#pragma unroll
  for (int j = 0; j < 8; ++j) {
    const int k = ks * 32 + kg * 8 + j;
    float f = 0.f;
    if (k < 2 * kH && col < kOut) {
      const int i = k >> 1;
      const float* p = &Wf[(((size_t)m * kH + i) * kOut + col) * 2];
      f = (k & 1) ? -p[1] : p[0];
    }
    v[j] = (f16)f;
  }
  *(f16x8*)&ws[kWfOff + ((size_t)c * kKS + ks) * 512 + lane * 8] = v;
}

// ---- one hidden layer: GEMM (64 rows x 768 cols, K=384) + Gabor activation.
// Wave tile 64x48 (3 n-tiles register-blocked), B-frags straight from global.
__device__ __forceinline__ void hidden_gemm(
    const char* __restrict__ Xs, char* __restrict__ Xd,
    const f16x8* __restrict__ wl,
    const float* __restrict__ ba, const float* __restrict__ bb,
    int w, int lane)
{
  const int kg = lane >> 4, l15 = lane & 15;
  const int comp = l15 & 3;
#pragma unroll
  for (int g = 0; g < 4; ++g) {
    const int nt0 = w * 12 + g * 3;
    f32x4 acc[4][3];
#pragma unroll
    for (int tn = 0; tn < 3; ++tn) {
      const int q = (nt0 + tn) * 4 + (l15 >> 2);
      float bv = 0.f;
      if (q < kH) bv = ((comp & 2) ? bb : ba)[q * 2 + (comp & 1)];
#pragma unroll
      for (int mt = 0; mt < 4; ++mt) acc[mt][tn] = {bv, bv, bv, bv};
    }
    f16x8 aC[4], bC[3], aN[4], bN[3];
#pragma unroll
    for (int tn = 0; tn < 3; ++tn) bC[tn] = wl[((size_t)(nt0 + tn) * kKS) * 64 + lane];
#pragma unroll
    for (int mt = 0; mt < 4; ++mt)
      aC[mt] = *(const f16x8*)(Xs + swz(l15 + 16 * mt, kg * 16));
#pragma unroll
    for (int ks = 0; ks < kKS; ++ks) {
      if (ks + 1 < kKS) {   // prefetch next k-step
#pragma unroll
        for (int tn = 0; tn < 3; ++tn)
          bN[tn] = wl[((size_t)(nt0 + tn) * kKS + ks + 1) * 64 + lane];
#pragma unroll
        for (int mt = 0; mt < 4; ++mt)
          aN[mt] = *(const f16x8*)(Xs + swz(l15 + 16 * mt, (ks + 1) * 64 + kg * 16));
      }
#pragma unroll
      for (int mt = 0; mt < 4; ++mt)
#pragma unroll
        for (int tn = 0; tn < 3; ++tn)
          acc[mt][tn] = __builtin_amdgcn_mfma_f32_16x16x32_f16(aC[mt], bC[tn], acc[mt][tn], 0, 0, 0);
#pragma unroll
      for (int mt = 0; mt < 4; ++mt) aC[mt] = aN[mt];
#pragma unroll
      for (int tn = 0; tn < 3; ++tn) bC[tn] = bN[tn];
    }
    // Gabor activation; comp0 lane gathers (la_re, la_im, lb_re, lb_im) of its
    // (row, neuron) from the 4-lane group and writes packed (re,im) fp16.
#pragma unroll
    for (int mt = 0; mt < 4; ++mt)
#pragma unroll
      for (int tn = 0; tn < 3; ++tn) {
        const int q = (nt0 + tn) * 4 + (l15 >> 2);
#pragma unroll
        for (int j = 0; j < 4; ++j) {
          const float v0 = acc[mt][tn][j];
          const float v1 = __shfl_xor(v0, 1, 64);
          const float v2 = __shfl_xor(v0, 2, 64);
          const float v3 = __shfl_xor(v1, 2, 64);
          const float mag = kS2 * (v0 * v0 + v1 * v1 + v2 * v2 + v3 * v3);
          const float amp = __expf(fmaf(-kOmega, v1, -mag));
          const float ph = kOmega * v0;
          f16x2 pv = {(f16)(amp * __cosf(ph)), (f16)(amp * __sinf(ph))};
          if (comp == 0) {
            const int row = mt * 16 + kg * 4 + j;   // C-layout: row=4*(l>>4)+reg
            *(f16x2*)(Xd + swz(row, q * 4)) = pv;
          }
        }
      }
  }
}

__global__ __launch_bounds__(256, 1) void wire_main(
    const float* __restrict__ inp, const int* __restrict__ indices,
    const int* __restrict__ model_idx, const int* __restrict__ bias_idx,
    const float* __restrict__ W0a, const float* __restrict__ b0a,
    const float* __restrict__ W0b, const float* __restrict__ b0b,
    const float* __restrict__ b1a, const float* __restrict__ b1b,
    const float* __restrict__ b2a, const float* __restrict__ b2b,
    const float* __restrict__ bf, const f16* __restrict__ wsW,
    float* __restrict__ out)
{
  __shared__ __align__(16) char X[2][kMB * kRowB];   // 2 x 48 KB ping-pong
  const int d = blockIdx.x;
  const int lg = (d & 7) * 256 + (d >> 3);   // XCD swizzle (2048 % 8 == 0)
  const int c = lg >> 7;
  const int n0 = (lg & 127) * kMB;
  const int src = indices[c], m = model_idx[c], bix = bias_idx[c];
  const int tid = threadIdx.x, w = tid >> 6, lane = tid & 63;

  // ---- layer 0 (VALU, f32): real 2->181 + activation, write X[0] fp16
  {
    const int r = tid >> 2, sub = tid & 3;
    const float2 xv = *(const float2*)&inp[((size_t)src * kN + n0 + r) * 2];
    for (int o = sub; o < 192; o += 4) {   // cover pad neurons -> (1,0)
      float la = 0.f, lb = 0.f;
      if (o < kH) {
        la = fmaf(xv.y, W0a[(m * 2 + 1) * kH + o], fmaf(xv.x, W0a[(m * 2) * kH + o], b0a[bix * kH + o]));
        lb = fmaf(xv.y, W0b[(m * 2 + 1) * kH + o], fmaf(xv.x, W0b[(m * 2) * kH + o], b0b[bix * kH + o]));
      }
      const float amp = __expf(-kS2 * fmaf(la, la, lb * lb));
      const float ph = kOmega * la;
      f16x2 pv = {(f16)(amp * __cosf(ph)), (f16)(amp * __sinf(ph))};
      *(f16x2*)(&X[0][0] + swz(r, o * 4)) = pv;
    }
  }
  __syncthreads();
  hidden_gemm(X[0], X[1], (const f16x8*)(wsW + (size_t)(c * 2 + 0) * kWLayerStride),
              b1a + (size_t)bix * kH * 2, b1b + (size_t)bix * kH * 2, w, lane);
  __syncthreads();
  hidden_gemm(X[1], X[0], (const f16x8*)(wsW + (size_t)(c * 2 + 1) * kWLayerStride),
              b2a + (size_t)bix * kH * 2, b2b + (size_t)bix * kH * 2, w, lane);
  __syncthreads();
  // ---- final complex 181->3, real part, via one MFMA n-tile (wave w = m-tile w)
  {
    const int kg = lane >> 4, l15 = lane & 15;
    const f16x8* wf = (const f16x8*)(wsW + kWfOff + (size_t)c * kWfStride);
    f32x4 facc = {0.f, 0.f, 0.f, 0.f};
#pragma unroll
    for (int ks = 0; ks < kKS; ++ks) {
      f16x8 a = *(const f16x8*)(&X[0][0] + swz(l15 + 16 * w, ks * 64 + kg * 16));
      f16x8 b = wf[(size_t)ks * 64 + lane];
      facc = __builtin_amdgcn_mfma_f32_16x16x32_f16(a, b, facc, 0, 0, 0);
    }
    if (l15 < kOut) {
      const float bfr = bf[(bix * kOut + l15) * 2];
#pragma unroll
      for (int j = 0; j < 4; ++j) {
        const int row = w * 16 + kg * 4 + j;
        out[((size_t)c * kN + n0 + row) * kOut + l15] = facc[j] + bfr;
      }
    }
  }
}

}  // namespace

extern "C" void kernel_launch(void* const* d_in, const int* in_sizes, int n_in,
                              void* d_out, int out_size, void* d_ws, size_t ws_size,
                              hipStream_t stream) {
  const float* inp       = (const float*)d_in[0];
  const int*   indices   = (const int*)  d_in[1];
  const int*   model_idx = (const int*)  d_in[2];
  const int*   bias_idx  = (const int*)  d_in[3];
  const float* W0a = (const float*)d_in[4];
  const float* b0a = (const float*)d_in[5];
  const float* W0b = (const float*)d_in[6];
  const float* b0b = (const float*)d_in[7];
  const float* W1a = (const float*)d_in[8];
  const float* b1a = (const float*)d_in[9];
  const float* W1b = (const float*)d_in[10];
  const float* b1b = (const float*)d_in[11];
  const float* W2a = (const float*)d_in[12];
  const float* b2a = (const float*)d_in[13];
  const float* W2b = (const float*)d_in[14];
  const float* b2b = (const float*)d_in[15];
  const float* Wf  = (const float*)d_in[16];
  const float* bff = (const float*)d_in[17];
  f16*   ws  = (f16*)d_ws;     // needs ~19.1 MB
  float* out = (float*)d_out;

  prep_hidden<<<dim3(kC * 2 * kNT), dim3(768), 0, stream>>>(model_idx, W1a, W1b, W2a, W2b, ws);
  prep_final<<<dim3(kC), dim3(768), 0, stream>>>(model_idx, Wf, ws);
  wire_main<<<dim3(kC * (kN / kMB)), dim3(256), 0, stream>>>(
      inp, indices, model_idx, bias_idx, W0a, b0a, W0b, b0b,
      b1a, b1b, b2a, b2b, bff, ws, out);
}